// Round 18
// baseline (505.183 us; speedup 1.0000x reference)
//
#include <hip/hip_runtime.h>

#define NPTS 1000000
#define NVOX 200000
#define EPSV 1e-5f

#define KB2 768     // k4 blocks (512 thr = 8 waves) -> 6144 waves
#define KB6 768     // k6_gather blocks (fallback)
#define KB7 768     // k7 blocks (fallback)
#define KB6S 782    // k6_stream blocks (512 thr = 8 waves): 6250 active waves
#define MOMB 512    // k_mom blocks
#define NMB ((NVOX + 255) / 256)   // 782 (k_mean blocks)

#define W2CH 176    // pts/wave (k4): 176%16==0
#define V6CH ((NVOX + KB6*4 - 1) / (KB6*4))     // 66 vox/wave (k6_gather)
#define V7CH ((NVOX + KB7*4 - 1) / (KB7*4))     // 66 vox/wave (k7)
#define V6SCH 32    // vox/wave (k6_stream): 200000 = 6250*32

// ================= ws layouts (4-byte word offsets) =================
// --- compact layout (fallback; ~9.5 MB) ---
#define OFF_CNT    0
#define ZERO_WORDS 200000
#define OFF_BASE   200000
#define OFF_BSUM   400000
#define OFF_BOFF   400512
#define OFF_PIDX   401024
#define OFF_VOX    1401024     // 800000 (16B aligned)
#define OFF_MOM    2201024     // MOMB*104 = 53248
#define OFF_PH2    2254272     // KB2*64 = 49152
#define OFF_PQ2    2303424
#define OFF_WF2    2352576     // 832
#define OFF_BF2    2353408     // 64
#define OFF_S2     2353472
#define OFF_T2     2353536
#define OFF_MU     2353600     // 16
#define OFF_BF2C   2353616     // 64

// --- fast layout ---
#define F_BASE   0             // 200000   live: scan .. k6_stream
#define F_VOX    200000        // 800000   live: k_mean .. k4 (16B aligned)
#define F_PH2    1000000       // 49152    live: k4 .. k5
#define F_PQ2    1049152       // 49152
#define F_WF2    1098304       // 832
#define F_BF2    1099136       // 64
#define F_S2     1099200       // 64
#define F_T2     1099264       // 64
#define F_MU     1099328       // 16 (13 means, padded)
#define F_BF2C   1099344       // 64 (bias with means folded in)
#define F_SIDX   1099408       // 1000000  live: k_fill .. k4
#define F_H      2099408       // h: fp16 32e6 halves
// early-dead overlay inside h region:
#define F_CNT    2099408       // 200000   k_count..k_scan1
#define F_BSUM   2299408       // 512
#define F_BOFF   2299920       // 512
#define F_PIDX   2300432       // 1000000  k_fill..k_mean
#define F_MOM    3300432       // 53248    k_mom..k_fold_all

#define NEED_F16_BYTES ((size_t)F_H * 4 + (size_t)NPTS * 64 * 2)  // 136,397,632

#define SCAN_B 512
#define NSCAN ((NVOX + SCAN_B - 1) / SCAN_B)   // 391

#define TRI(j,k) ((j)*13 - (j)*((j)-1)/2 + ((k)-(j)))

typedef _Float16 f16x8 __attribute__((ext_vector_type(8)));
typedef float f32x4 __attribute__((ext_vector_type(4)));

__device__ __forceinline__ float bcast(float x, int k) {
    return __int_as_float(__builtin_amdgcn_readlane(__float_as_int(x), k));
}
__device__ __forceinline__ float wave_red(float x) {
#pragma unroll
    for (int o = 32; o > 0; o >>= 1) x += __shfl_down(x, o);
    return x;
}

// ---- macro-generated straight-line register code ----
#define REP13(M) M(0) M(1) M(2) M(3) M(4) M(5) M(6) M(7) M(8) M(9) M(10) M(11) M(12)
#define REP64(M) M(0) M(1) M(2) M(3) M(4) M(5) M(6) M(7) M(8) M(9) \
 M(10) M(11) M(12) M(13) M(14) M(15) M(16) M(17) M(18) M(19) \
 M(20) M(21) M(22) M(23) M(24) M(25) M(26) M(27) M(28) M(29) \
 M(30) M(31) M(32) M(33) M(34) M(35) M(36) M(37) M(38) M(39) \
 M(40) M(41) M(42) M(43) M(44) M(45) M(46) M(47) M(48) M(49) \
 M(50) M(51) M(52) M(53) M(54) M(55) M(56) M(57) M(58) M(59) \
 M(60) M(61) M(62) M(63)

#define DECL_W1(J)  float w1c_##J = Wfp[(J)*64 + lane]; asm("" : "+v"(w1c_##J));
#define DECL_W2(K)  float w2c_##K = w2[(K)*64 + lane];  asm("" : "+v"(w2c_##K));
#define DECL_W3(K)  float w3c_##K = w3[(K)*64 + lane];  asm("" : "+v"(w3c_##K));

#define FEAT_BODY \
    float4 pt = pts[p]; \
    int g0 = gind[3*p], g1 = gind[3*p+1], g2 = gind[3*p+2]; \
    float f0 = pt.x, f1 = pt.y, f2 = pt.z, f3 = pt.w; \
    float f4 = pt.x - vs.x, f5 = pt.y - vs.y, f6 = pt.z - vs.z; \
    float f7 = pt.x - ((float)g0 * 0.2f - 51.2f); \
    float f8 = pt.y - ((float)g1 * 0.2f - 51.2f); \
    float f9 = pt.z - ((float)g2 * 0.2f - 4.0f); \
    float f10 = nor[3*p], f11 = nor[3*p+1], f12 = nor[3*p+2];

#define L1EXPR (bc + ((((f0*w1c_0 + f1*w1c_1) + (f2*w1c_2 + f3*w1c_3)) \
              + ((f4*w1c_4 + f5*w1c_5) + (f6*w1c_6 + f7*w1c_7))) \
              + (((f8*w1c_8 + f9*w1c_9) + (f10*w1c_10 + f11*w1c_11)) \
              + f12*w1c_12)))

#define L2G(A,B,C,D) ha += bcast(r,A)*w2c_##A; hb += bcast(r,B)*w2c_##B; \
                     hc += bcast(r,C)*w2c_##C; hd += bcast(r,D)*w2c_##D;
#define L2ALL L2G(0,1,2,3) L2G(4,5,6,7) L2G(8,9,10,11) L2G(12,13,14,15) \
  L2G(16,17,18,19) L2G(20,21,22,23) L2G(24,25,26,27) L2G(28,29,30,31) \
  L2G(32,33,34,35) L2G(36,37,38,39) L2G(40,41,42,43) L2G(44,45,46,47) \
  L2G(48,49,50,51) L2G(52,53,54,55) L2G(56,57,58,59) L2G(60,61,62,63)

#define L3G(A,B,C,D) ya += bcast(m,A)*w3c_##A; yb += bcast(m,B)*w3c_##B; \
                     yc += bcast(m,C)*w3c_##C; yd += bcast(m,D)*w3c_##D;
#define L3ALL L3G(0,1,2,3) L3G(4,5,6,7) L3G(8,9,10,11) L3G(12,13,14,15) \
  L3G(16,17,18,19) L3G(20,21,22,23) L3G(24,25,26,27) L3G(28,29,30,31) \
  L3G(32,33,34,35) L3G(36,37,38,39) L3G(40,41,42,43) L3G(44,45,46,47) \
  L3G(48,49,50,51) L3G(52,53,54,55) L3G(56,57,58,59) L3G(60,61,62,63)

// ---------------- counts ----------------
__global__ __launch_bounds__(256) void k_count(
    const int* __restrict__ cinv, int* __restrict__ cnt)
{
    int i = blockIdx.x * 256 + threadIdx.x;
    if (i < NPTS) atomicAdd(&cnt[cinv[i]], 1);
}

// ---------------- scan ----------------
__global__ __launch_bounds__(SCAN_B) void k_scan1(
    const int* __restrict__ cnt, int* __restrict__ base, int* __restrict__ bsum)
{
    __shared__ int sd[SCAN_B];
    int t = threadIdx.x;
    int v = blockIdx.x * SCAN_B + t;
    int x = (v < NVOX) ? cnt[v] : 0;
    sd[t] = x;
    __syncthreads();
    for (int o = 1; o < SCAN_B; o <<= 1) {
        int y = (t >= o) ? sd[t - o] : 0;
        __syncthreads();
        sd[t] += y;
        __syncthreads();
    }
    if (v < NVOX) base[v] = sd[t] - x;
    if (t == SCAN_B - 1) bsum[blockIdx.x] = sd[t];
}

__global__ __launch_bounds__(SCAN_B) void k_scan2(
    const int* __restrict__ bsum, int* __restrict__ boff)
{
    __shared__ int sd[SCAN_B];
    int t = threadIdx.x;
    int x = (t < NSCAN) ? bsum[t] : 0;
    sd[t] = x;
    __syncthreads();
    for (int o = 1; o < SCAN_B; o <<= 1) {
        int y = (t >= o) ? sd[t - o] : 0;
        __syncthreads();
        sd[t] += y;
        __syncthreads();
    }
    if (t < NSCAN) boff[t] = sd[t] - x;
}

__global__ __launch_bounds__(256) void k_base(
    const int* __restrict__ boff, int* __restrict__ base)
{
    int v = blockIdx.x * 256 + threadIdx.x;
    if (v < NVOX) base[v] += boff[v >> 9];
}

__global__ __launch_bounds__(256) void k_fill(
    const int* __restrict__ cinv, int* __restrict__ base,
    int* __restrict__ pidx, int* __restrict__ sidx)
{
    int i = blockIdx.x * 256 + threadIdx.x;
    if (i >= NPTS) return;
    int slot = atomicAdd(&base[cinv[i]], 1);
    pidx[slot] = i;
    if (sidx) sidx[i] = slot;
}

// ---------------- per-voxel means ----------------
__global__ __launch_bounds__(256, 2) void k_mean(
    const float4* __restrict__ pts, const int* __restrict__ base,
    const int* __restrict__ pidx, float4* __restrict__ vox4)
{
    int v = blockIdx.x * 256 + threadIdx.x;
    if (v >= NVOX) return;
    int st = (v == 0) ? 0 : base[v - 1];
    int en = base[v];
    int c = en - st;
    float sx = 0.f, sy = 0.f, sz = 0.f;
    for (int i = st; i < en; i++) {
        float4 p = pts[pidx[i]];
        sx += p.x; sy += p.y; sz += p.z;
    }
    float fc = (float)c;
    float ic = 1.0f / fmaxf(fc, 1.0f);
    vox4[v] = make_float4(sx * ic, sy * ic, sz * ic, fc);
}

// -------- feature moments: E[f] (13) + E[f f^T] upper-tri (91) -> partials --
__global__ __launch_bounds__(256) void k_mom(
    const float4* __restrict__ pts, const float* __restrict__ nor,
    const int* __restrict__ gind, const int* __restrict__ cinv,
    const float4* __restrict__ vox4, float* __restrict__ MOMP)
{
    const int T = MOMB * 256;
    int tid = blockIdx.x * 256 + threadIdx.x;
    float s[13], q[91];
#pragma unroll
    for (int j = 0; j < 13; j++) s[j] = 0.f;
#pragma unroll
    for (int j = 0; j < 91; j++) q[j] = 0.f;
    for (int i = tid; i < NPTS; i += T) {
        float4 p = pts[i];
        int g0 = gind[3*i], g1 = gind[3*i+1], g2 = gind[3*i+2];
        float n0 = nor[3*i], n1 = nor[3*i+1], n2 = nor[3*i+2];
        float4 vs = vox4[cinv[i]];
        float f[13];
        f[0] = p.x; f[1] = p.y; f[2] = p.z; f[3] = p.w;
        f[4] = p.x - vs.x; f[5] = p.y - vs.y; f[6] = p.z - vs.z;
        f[7] = p.x - ((float)g0 * 0.2f - 51.2f);
        f[8] = p.y - ((float)g1 * 0.2f - 51.2f);
        f[9] = p.z - ((float)g2 * 0.2f - 4.0f);
        f[10] = n0; f[11] = n1; f[12] = n2;
#pragma unroll
        for (int j = 0; j < 13; j++) s[j] += f[j];
#pragma unroll
        for (int j = 0; j < 13; j++)
#pragma unroll
            for (int k = j; k < 13; k++) q[TRI(j,k)] += f[j] * f[k];
    }
#pragma unroll
    for (int j = 0; j < 13; j++) s[j] = wave_red(s[j]);
#pragma unroll
    for (int j = 0; j < 91; j++) q[j] = wave_red(q[j]);
    __shared__ float red[4][104];
    int w = threadIdx.x >> 6, lane = threadIdx.x & 63;
    if (lane == 0) {
#pragma unroll
        for (int j = 0; j < 13; j++) red[w][j] = s[j];
#pragma unroll
        for (int j = 0; j < 91; j++) red[w][13 + j] = q[j];
    }
    __syncthreads();
    int t = threadIdx.x;
    if (t < 104)
        MOMP[blockIdx.x * 104 + t] = red[0][t] + red[1][t] + red[2][t] + red[3][t];
}

// ---- reduce moments; fold BN0+BN1 -> Wf2, bf2 (raw), bf2c (centered), MU ---
__global__ void k_fold_all(
    const float* __restrict__ MOMP,
    const float* __restrict__ bn0g, const float* __restrict__ bn0b,
    const float* __restrict__ w1, const float* __restrict__ b1,
    const float* __restrict__ bn1g, const float* __restrict__ bn1b,
    float* __restrict__ Wf2, float* __restrict__ bf2,
    float* __restrict__ MUo, float* __restrict__ bf2c)
{
    __shared__ float mom[104];
    __shared__ float mu[13];
    __shared__ float C[13][13];
    int t = threadIdx.x;  // 128 threads
    for (int j = t; j < 104; j += 128) {
        float s = 0.f;
        for (int b = 0; b < MOMB; b++) s += MOMP[b * 104 + j];
        mom[j] = s;
    }
    __syncthreads();
    const float invN = 1.0f / (float)NPTS;
    if (t < 13) mu[t] = mom[t] * invN;
    __syncthreads();
    for (int e = t; e < 91; e += 128) {
        int j = 0, r = e;
        while (r >= 13 - j) { r -= 13 - j; j++; }
        int k = j + r;
        float v = mom[13 + e] * invN - mu[j] * mu[k];
        C[j][k] = v; C[k][j] = v;
    }
    __syncthreads();
    if (t < 16) MUo[t] = (t < 13) ? mu[t] : 0.f;
    if (t < 64) {
        float s0[13], t0[13];
#pragma unroll
        for (int j = 0; j < 13; j++) {
            float sc = bn0g[j] * rsqrtf(C[j][j] + EPSV);
            s0[j] = sc; t0[j] = bn0b[j] - mu[j] * sc;
        }
        float wt[13];
        float bt = b1[t];
#pragma unroll
        for (int j = 0; j < 13; j++) {
            float w = w1[j*64 + t];
            wt[j] = s0[j] * w;
            bt += t0[j] * w;
        }
        float mean1 = bt;
#pragma unroll
        for (int j = 0; j < 13; j++) mean1 += wt[j] * mu[j];
        float var1 = 0.f;
#pragma unroll
        for (int j = 0; j < 13; j++) {
            float acc = 0.f;
#pragma unroll
            for (int k = 0; k < 13; k++) acc += wt[k] * C[j][k];
            var1 += wt[j] * acc;
        }
        float s1 = bn1g[t] * rsqrtf(var1 + EPSV);
        float t1 = bn1b[t] - mean1 * s1;
        float bfo = s1 * bt + t1;
        float bfc = bfo;
#pragma unroll
        for (int j = 0; j < 13; j++) {
            float wv = s1 * wt[j];
            Wf2[j*64 + t] = wv;
            bfc += wv * mu[j];
        }
        bf2[t] = bfo;
        bf2c[t] = bfc;
    }
}

// ------------- k4: L1 AND L2 via MFMA fp16 (features mean-centered) ---------
// Staging lanes 0-15 each compute their OWN point's 13 centered features
// (fp16, O(1-5) magnitude -> err ~2e-3), write to FS (m92 layout, K padded
// to 32 with zeros). L1 = 4 MFMAs with bias(bf2c) in C-in -> relu -> RS.
// L2 = 8 MFMAs (unchanged, verified). D readout m89.
template <typename HT>
__global__ __launch_bounds__(512) void k4_stats2(
    const float4* __restrict__ pts, const float* __restrict__ nor,
    const int* __restrict__ gind, const int* __restrict__ cinv,
    const float4* __restrict__ vox4,
    const float* __restrict__ Wf2, const float* __restrict__ bf2c,
    const float* __restrict__ MU, const float* __restrict__ w2,
    const int* __restrict__ sidx, HT* __restrict__ hout,
    float* __restrict__ PH, float* __restrict__ PQ)
{
    int lane = threadIdx.x & 63;
    int w = threadIdx.x >> 6;      // 0..7
    int wid = blockIdx.x * 8 + w;
    int p0 = wid * W2CH;
    int p1 = min(p0 + W2CH, NPTS);
    int cl = lane & 15;            // col within 16
    int kg = lane >> 4;            // k-group / row-group

    __shared__ __align__(16) _Float16 RS[8][16 * 80];  // r (post-relu) staging
    __shared__ __align__(16) _Float16 FS[8][16 * 80];  // feature staging
    __shared__ int SLT[8][16];
    __shared__ float CENL[8][48];
    __shared__ float NORL[8][48];
    __shared__ float MUL[16];
    __shared__ float LH[8][64], LQ[8][64];

    if (threadIdx.x < 16) MUL[threadIdx.x] = MU[threadIdx.x];
    __syncthreads();

    // L1 B-frags from Wf2 (13x64, K padded to 32)
    f16x8 wf1[4];
#pragma unroll
    for (int t = 0; t < 4; t++) {
        f16x8 v;
#pragma unroll
        for (int j = 0; j < 8; j++) {
            int k = kg * 8 + j;
            v[j] = (k < 13) ? (_Float16)Wf2[k * 64 + t * 16 + cl] : (_Float16)0.f;
        }
        wf1[t] = v;
    }
    float bb0 = bf2c[cl], bb1 = bf2c[16 + cl], bb2 = bf2c[32 + cl], bb3 = bf2c[48 + cl];

    // L2 B-frags from w2 (64x64)
    f16x8 wf[8];
#pragma unroll
    for (int t = 0; t < 4; t++)
#pragma unroll
        for (int h = 0; h < 2; h++) {
            f16x8 v;
#pragma unroll
            for (int j = 0; j < 8; j++) {
                int k = h * 32 + kg * 8 + j;
                v[j] = (_Float16)w2[k * 64 + t * 16 + cl];
            }
            wf[t * 2 + h] = v;
        }

    float sh0 = 0.f, sh1 = 0.f, sh2 = 0.f, sh3 = 0.f;
    float sq0 = 0.f, sq1 = 0.f, sq2 = 0.f, sq3 = 0.f;

    _Float16* rs = RS[w];
    _Float16* fs = FS[w];
    int* slt = SLT[w];
    float* cel = CENL[w];
    float* nol = NORL[w];

    // zero-pad FS k=13..31 once (per-batch writes only touch k<13)
    if (lane < 16) {
#pragma unroll
        for (int k = 13; k < 32; k++) fs[lane * 80 + k] = (_Float16)0.f;
    }

    for (int pb = p0; pb < p1; pb += 16) {
        // ---- staging ----
        if (lane < 48) {
            int gv = gind[3 * pb + lane];        // coalesced 48 dwords
            int comp = lane % 3;
            cel[lane] = (float)gv * 0.2f - ((comp == 2) ? 4.0f : 51.2f);
            nol[lane] = nor[3 * pb + lane];      // coalesced
        }
        if (lane < 16) {
            int p = pb + lane;
            float4 pt = pts[p];
            float4 vs = vox4[cinv[p]];           // 16 parallel gathers
            if (sidx) slt[lane] = sidx[p];
            float g0 = pt.x - MUL[0], g1 = pt.y - MUL[1];
            float g2 = pt.z - MUL[2], g3 = pt.w - MUL[3];
            float g4 = pt.x - vs.x - MUL[4];
            float g5 = pt.y - vs.y - MUL[5];
            float g6 = pt.z - vs.z - MUL[6];
            float g7 = pt.x - cel[3*lane]   - MUL[7];
            float g8 = pt.y - cel[3*lane+1] - MUL[8];
            float g9 = pt.z - cel[3*lane+2] - MUL[9];
            float g10 = nol[3*lane]   - MUL[10];
            float g11 = nol[3*lane+1] - MUL[11];
            float g12 = nol[3*lane+2] - MUL[12];
            _Float16* fr = fs + lane * 80;
            fr[0]=(_Float16)g0;  fr[1]=(_Float16)g1;  fr[2]=(_Float16)g2;
            fr[3]=(_Float16)g3;  fr[4]=(_Float16)g4;  fr[5]=(_Float16)g5;
            fr[6]=(_Float16)g6;  fr[7]=(_Float16)g7;  fr[8]=(_Float16)g8;
            fr[9]=(_Float16)g9;  fr[10]=(_Float16)g10; fr[11]=(_Float16)g11;
            fr[12]=(_Float16)g12;
        }
        // ---- L1 via MFMA: D = feats x Wf2 + bf2c ----
        const _Float16* af = fs + cl * 80 + kg * 8;
        f16x8 fa = *(const f16x8*)af;            // K=32 (13 real + zeros)
        f32x4 r0 = {bb0, bb0, bb0, bb0};
        f32x4 r1 = {bb1, bb1, bb1, bb1};
        f32x4 r2 = {bb2, bb2, bb2, bb2};
        f32x4 r3 = {bb3, bb3, bb3, bb3};
        r0 = __builtin_amdgcn_mfma_f32_16x16x32_f16(fa, wf1[0], r0, 0, 0, 0);
        r1 = __builtin_amdgcn_mfma_f32_16x16x32_f16(fa, wf1[1], r1, 0, 0, 0);
        r2 = __builtin_amdgcn_mfma_f32_16x16x32_f16(fa, wf1[2], r2, 0, 0, 0);
        r3 = __builtin_amdgcn_mfma_f32_16x16x32_f16(fa, wf1[3], r3, 0, 0, 0);
        // relu -> RS[point][channel]  (row m = kg*4+r, col = T*16+cl)
#define RELU_STORE(T, ACC) { \
        _Pragma("unroll") \
        for (int r = 0; r < 4; r++) { \
            int m = kg * 4 + r; \
            rs[m * 80 + (T)*16 + cl] = (_Float16)fmaxf(ACC[r], 0.f); \
        } }
        RELU_STORE(0, r0)
        RELU_STORE(1, r1)
        RELU_STORE(2, r2)
        RELU_STORE(3, r3)
#undef RELU_STORE
        // ---- L2 via MFMA (verified path) ----
        const _Float16* arow = rs + cl * 80 + kg * 8;
        f16x8 a0 = *(const f16x8*)(arow);        // k 0..31
        f16x8 a1 = *(const f16x8*)(arow + 32);   // k 32..63
        f32x4 acc0 = {0.f, 0.f, 0.f, 0.f};
        f32x4 acc1 = {0.f, 0.f, 0.f, 0.f};
        f32x4 acc2 = {0.f, 0.f, 0.f, 0.f};
        f32x4 acc3 = {0.f, 0.f, 0.f, 0.f};
        acc0 = __builtin_amdgcn_mfma_f32_16x16x32_f16(a0, wf[0], acc0, 0, 0, 0);
        acc0 = __builtin_amdgcn_mfma_f32_16x16x32_f16(a1, wf[1], acc0, 0, 0, 0);
        acc1 = __builtin_amdgcn_mfma_f32_16x16x32_f16(a0, wf[2], acc1, 0, 0, 0);
        acc1 = __builtin_amdgcn_mfma_f32_16x16x32_f16(a1, wf[3], acc1, 0, 0, 0);
        acc2 = __builtin_amdgcn_mfma_f32_16x16x32_f16(a0, wf[4], acc2, 0, 0, 0);
        acc2 = __builtin_amdgcn_mfma_f32_16x16x32_f16(a1, wf[5], acc2, 0, 0, 0);
        acc3 = __builtin_amdgcn_mfma_f32_16x16x32_f16(a0, wf[6], acc3, 0, 0, 0);
        acc3 = __builtin_amdgcn_mfma_f32_16x16x32_f16(a1, wf[7], acc3, 0, 0, 0);
        int s0v = 0, s1v = 0, s2v = 0, s3v = 0;
        if (sidx) {
            s0v = slt[kg * 4 + 0]; s1v = slt[kg * 4 + 1];
            s2v = slt[kg * 4 + 2]; s3v = slt[kg * 4 + 3];
        }
#define TILE_OUT(T, ACC) { \
        float d0 = ACC[0], d1 = ACC[1], d2 = ACC[2], d3 = ACC[3]; \
        sh##T += (d0 + d1) + (d2 + d3); \
        sq##T += (d0*d0 + d1*d1) + (d2*d2 + d3*d3); \
        if (hout) { \
            hout[(size_t)s0v * 64 + (T)*16 + cl] = (HT)d0; \
            hout[(size_t)s1v * 64 + (T)*16 + cl] = (HT)d1; \
            hout[(size_t)s2v * 64 + (T)*16 + cl] = (HT)d2; \
            hout[(size_t)s3v * 64 + (T)*16 + cl] = (HT)d3; \
        } }
        TILE_OUT(0, acc0)
        TILE_OUT(1, acc1)
        TILE_OUT(2, acc2)
        TILE_OUT(3, acc3)
#undef TILE_OUT
    }
    // column totals: combine lanes {l, l^16, l^32, l^48}
#define COLRED(V) { V += __shfl_xor(V, 16); V += __shfl_xor(V, 32); }
    COLRED(sh0) COLRED(sh1) COLRED(sh2) COLRED(sh3)
    COLRED(sq0) COLRED(sq1) COLRED(sq2) COLRED(sq3)
#undef COLRED
    if (lane < 16) {
        LH[w][cl]      = sh0; LH[w][16 + cl] = sh1;
        LH[w][32 + cl] = sh2; LH[w][48 + cl] = sh3;
        LQ[w][cl]      = sq0; LQ[w][16 + cl] = sq1;
        LQ[w][32 + cl] = sq2; LQ[w][48 + cl] = sq3;
    }
    __syncthreads();
    if (w == 0) {
        float a = 0.f, b = 0.f;
#pragma unroll
        for (int x = 0; x < 8; x++) { a += LH[x][lane]; b += LQ[x][lane]; }
        PH[blockIdx.x * 64 + lane] = a;
        PQ[blockIdx.x * 64 + lane] = b;
    }
}

// ---------------- reduce + finalize BN2 (stats are of h' = h - b2) ----------
__global__ __launch_bounds__(256) void k5_bn2(
    const float* __restrict__ PH, const float* __restrict__ PQ,
    const float* __restrict__ bn2g, const float* __restrict__ bn2b,
    float* __restrict__ s2, float* __restrict__ t2)
{
    __shared__ float LH[4][64], LQ[4][64];
    int c = threadIdx.x & 63, g = threadIdx.x >> 6;
    float sH = 0.f, sQ = 0.f;
    for (int b = g; b < KB2; b += 4) { sH += PH[b*64 + c]; sQ += PQ[b*64 + c]; }
    LH[g][c] = sH; LQ[g][c] = sQ;
    __syncthreads();
    if (g == 0) {
        const float invN = 1.0f / (float)NPTS;
        float mn = (LH[0][c] + LH[1][c] + LH[2][c] + LH[3][c]) * invN;
        float vr = (LQ[0][c] + LQ[1][c] + LQ[2][c] + LQ[3][c]) * invN - mn * mn;
        float s = bn2g[c] * rsqrtf(vr + EPSV);
        s2[c] = s; t2[c] = bn2b[c] - mn * s;
    }
}

// -------- FAST PATH k6: segmean of BN2(h')+relu, then w3 via MFMA -----------
template <typename HT>
__global__ __launch_bounds__(512) void k6_stream(
    const int* __restrict__ base, const HT* __restrict__ h,
    const float* __restrict__ s2, const float* __restrict__ t2,
    const float* __restrict__ w3, const float* __restrict__ b3,
    float* __restrict__ out)
{
    int lane = threadIdx.x & 63;
    int w = threadIdx.x >> 6;
    int wid = blockIdx.x * 8 + w;
    int v0 = wid * V6SCH;            // 32 voxels/wave, exact
    if (v0 >= NVOX) return;
    int cl = lane & 15, kg = lane >> 4;

    __shared__ __align__(16) _Float16 RS[8][16 * 80];  // mean staging
    __shared__ int BL[8][33];                          // base prefetch
    __shared__ int CNTL[8][16];                        // per-voxel counts

    float s2c = s2[lane], t2c = t2[lane];

    f16x8 wf[8];
#pragma unroll
    for (int t = 0; t < 4; t++)
#pragma unroll
        for (int hh = 0; hh < 2; hh++) {
            f16x8 v;
#pragma unroll
            for (int j = 0; j < 8; j++) {
                int k = hh * 32 + kg * 8 + j;
                v[j] = (_Float16)w3[k * 64 + t * 16 + cl];
            }
            wf[t * 2 + hh] = v;
        }
    float b3v0 = b3[cl], b3v1 = b3[16 + cl], b3v2 = b3[32 + cl], b3v3 = b3[48 + cl];

    _Float16* rs = RS[w];
    int* bl = BL[w];
    int* cntl = CNTL[w];

    if (lane < 33) {
        int idx = v0 - 1 + lane;
        bl[lane] = (idx < 0) ? 0 : base[idx];
    }

    for (int vb = 0; vb < V6SCH; vb += 16) {
        for (int m = 0; m < 16; m++) {
            int st = bl[vb + m];
            int en = bl[vb + m + 1];
            int c = en - st;
            const HT* hp = h + (size_t)st * 64 + lane;
            float accz = 0.f;
            int ii = 0;
            for (; ii + 3 < c; ii += 4) {
                float h0 = (float)hp[(size_t)(ii + 0) * 64];
                float h1 = (float)hp[(size_t)(ii + 1) * 64];
                float h2v = (float)hp[(size_t)(ii + 2) * 64];
                float h3v = (float)hp[(size_t)(ii + 3) * 64];
                accz += fmaxf(s2c * h0 + t2c, 0.f);
                accz += fmaxf(s2c * h1 + t2c, 0.f);
                accz += fmaxf(s2c * h2v + t2c, 0.f);
                accz += fmaxf(s2c * h3v + t2c, 0.f);
            }
            for (; ii < c; ii++)
                accz += fmaxf(s2c * (float)hp[(size_t)ii * 64] + t2c, 0.f);
            float inv = 1.0f / fmaxf((float)c, 1.0f);
            rs[m * 80 + lane] = (_Float16)(accz * inv);
            if (lane == 0) cntl[m] = c;
        }
        const _Float16* arow = rs + cl * 80 + kg * 8;
        f16x8 a0 = *(const f16x8*)(arow);
        f16x8 a1 = *(const f16x8*)(arow + 32);
        f32x4 acc0 = {0.f, 0.f, 0.f, 0.f};
        f32x4 acc1 = {0.f, 0.f, 0.f, 0.f};
        f32x4 acc2 = {0.f, 0.f, 0.f, 0.f};
        f32x4 acc3 = {0.f, 0.f, 0.f, 0.f};
        acc0 = __builtin_amdgcn_mfma_f32_16x16x32_f16(a0, wf[0], acc0, 0, 0, 0);
        acc0 = __builtin_amdgcn_mfma_f32_16x16x32_f16(a1, wf[1], acc0, 0, 0, 0);
        acc1 = __builtin_amdgcn_mfma_f32_16x16x32_f16(a0, wf[2], acc1, 0, 0, 0);
        acc1 = __builtin_amdgcn_mfma_f32_16x16x32_f16(a1, wf[3], acc1, 0, 0, 0);
        acc2 = __builtin_amdgcn_mfma_f32_16x16x32_f16(a0, wf[4], acc2, 0, 0, 0);
        acc2 = __builtin_amdgcn_mfma_f32_16x16x32_f16(a1, wf[5], acc2, 0, 0, 0);
        acc3 = __builtin_amdgcn_mfma_f32_16x16x32_f16(a0, wf[6], acc3, 0, 0, 0);
        acc3 = __builtin_amdgcn_mfma_f32_16x16x32_f16(a1, wf[7], acc3, 0, 0, 0);
        int vbase = v0 + vb;
#define OUT_TILE(T, ACC, B3) { \
        _Pragma("unroll") \
        for (int r = 0; r < 4; r++) { \
            int m = kg * 4 + r; \
            float d = ACC[r] + B3; \
            out[(size_t)(vbase + m) * 64 + (T)*16 + cl] = (cntl[m] > 0) ? d : 0.f; \
        } }
        OUT_TILE(0, acc0, b3v0)
        OUT_TILE(1, acc1, b3v1)
        OUT_TILE(2, acc2, b3v2)
        OUT_TILE(3, acc3, b3v3)
#undef OUT_TILE
    }
}

// ---- FALLBACK PATH: recompute h' (no b2; consistent with k5 stats) ---------
__global__ __launch_bounds__(256, 3) void k6_gather(
    const float4* __restrict__ pts, const float* __restrict__ nor,
    const int* __restrict__ gind,
    const int* __restrict__ base, const int* __restrict__ pidx,
    const float4* __restrict__ vox4,
    const float* __restrict__ Wfp, const float* __restrict__ bfv,
    const float* __restrict__ w2, const float* __restrict__ b2,
    const float* __restrict__ s2, const float* __restrict__ t2,
    float* __restrict__ out)
{
    int lane = threadIdx.x & 63;
    int wid = blockIdx.x * 4 + (threadIdx.x >> 6);
    int v0 = wid * V6CH, v1 = min(v0 + V6CH, NVOX);
    REP13(DECL_W1)
    float bc = bfv[lane];
    REP64(DECL_W2)
    float s2c = s2[lane], t2c = t2[lane];

    for (int v = v0; v < v1; v++) {
        int st = (v == 0) ? 0 : base[v - 1];
        int en = base[v];
        float4 vs = vox4[v];
        float accz = 0.f;
        for (int ii = st; ii < en; ii++) {
            int p = pidx[ii];
            FEAT_BODY
            float r = fmaxf(L1EXPR, 0.f);
            float ha = 0.f, hb = 0.f, hc = 0.f, hd = 0.f;
            L2ALL
            float h = (ha + hb) + (hc + hd);
            accz += fmaxf(s2c * h + t2c, 0.f);
        }
        out[(size_t)v * 64 + lane] = accz;
    }
}

// ---------- mean + w3 matmul + bias (in-place on d_out) — fallback only -----
__global__ __launch_bounds__(256, 3) void k7_final(
    const float4* __restrict__ vox4, const float* __restrict__ w3,
    const float* __restrict__ b3, float* __restrict__ out)
{
    int lane = threadIdx.x & 63;
    int wid = blockIdx.x * 4 + (threadIdx.x >> 6);
    int v0 = wid * V7CH, v1 = min(v0 + V7CH, NVOX);
    REP64(DECL_W3)
    float b3c = b3[lane];
    for (int v = v0; v < v1; v++) {
        float cnt = vox4[v].w;
        float* row = out + (size_t)v * 64;
        if (cnt > 0.5f) {
            float m = row[lane] / cnt;
            float ya = b3c, yb = 0.f, yc = 0.f, yd = 0.f;
            L3ALL
            row[lane] = (ya + yb) + (yc + yd);
        } else {
            row[lane] = 0.f;
        }
    }
}

extern "C" void kernel_launch(void* const* d_in, const int* in_sizes, int n_in,
                              void* d_out, int out_size, void* d_ws, size_t ws_size,
                              hipStream_t stream) {
    const float4* pts  = (const float4*)d_in[0];
    const float*  nor  = (const float*)d_in[1];
    const int*    gind = (const int*)d_in[2];
    const int*    cinv = (const int*)d_in[3];
    const float*  bn0g = (const float*)d_in[4];
    const float*  bn0b = (const float*)d_in[5];
    const float*  w1   = (const float*)d_in[6];
    const float*  b1   = (const float*)d_in[7];
    const float*  bn1g = (const float*)d_in[8];
    const float*  bn1b = (const float*)d_in[9];
    const float*  w2   = (const float*)d_in[10];
    const float*  b2   = (const float*)d_in[11];
    const float*  bn2g = (const float*)d_in[12];
    const float*  bn2b = (const float*)d_in[13];
    const float*  w3   = (const float*)d_in[14];
    const float*  b3   = (const float*)d_in[15];

    float* ws  = (float*)d_ws;
    float* out = (float*)d_out;

    // tier select: 1 = fp16-h fast path, 0 = recompute fallback
    int tier = 0;
    if (ws_size >= NEED_F16_BYTES) tier = 1;

    const bool fast = tier > 0;

    int*   cnt  = (int*)(ws + (fast ? F_CNT  : OFF_CNT));
    int*   base = (int*)(ws + (fast ? F_BASE : OFF_BASE));
    int*   bsum = (int*)(ws + (fast ? F_BSUM : OFF_BSUM));
    int*   boff = (int*)(ws + (fast ? F_BOFF : OFF_BOFF));
    int*   pidx = (int*)(ws + (fast ? F_PIDX : OFF_PIDX));
    float4* vox4 = (float4*)(ws + (fast ? F_VOX : OFF_VOX));
    float* MOMP = ws + (fast ? F_MOM : OFF_MOM);
    float* PH2  = ws + (fast ? F_PH2 : OFF_PH2);
    float* PQ2  = ws + (fast ? F_PQ2 : OFF_PQ2);
    float* Wf2  = ws + (fast ? F_WF2 : OFF_WF2);
    float* bf2  = ws + (fast ? F_BF2 : OFF_BF2);
    float* s2   = ws + (fast ? F_S2  : OFF_S2);
    float* t2   = ws + (fast ? F_T2  : OFF_T2);
    float* MUb  = ws + (fast ? F_MU  : OFF_MU);
    float* bf2c = ws + (fast ? F_BF2C: OFF_BF2C);
    int*   sidx = fast ? (int*)(ws + F_SIDX) : (int*)nullptr;
    void*  hbuf = fast ? (void*)(ws + F_H)   : nullptr;

    hipMemsetAsync(cnt, 0, (size_t)ZERO_WORDS * 4, stream);

    k_count<<<(NPTS + 255) / 256, 256, 0, stream>>>(cinv, cnt);
    k_scan1<<<NSCAN, SCAN_B, 0, stream>>>(cnt, base, bsum);
    k_scan2<<<1, SCAN_B, 0, stream>>>(bsum, boff);
    k_base<<<(NVOX + 255) / 256, 256, 0, stream>>>(boff, base);
    k_fill<<<(NPTS + 255) / 256, 256, 0, stream>>>(cinv, base, pidx, sidx);
    k_mean<<<NMB, 256, 0, stream>>>(pts, base, pidx, vox4);
    k_mom<<<MOMB, 256, 0, stream>>>(pts, nor, gind, cinv, vox4, MOMP);
    k_fold_all<<<1, 128, 0, stream>>>(MOMP, bn0g, bn0b, w1, b1, bn1g, bn1b,
                                      Wf2, bf2, MUb, bf2c);

    if (tier == 1) {
        k4_stats2<_Float16><<<KB2, 512, 0, stream>>>(pts, nor, gind, cinv, vox4,
                                                     Wf2, bf2c, MUb, w2,
                                                     sidx, (_Float16*)hbuf, PH2, PQ2);
    } else {
        k4_stats2<float><<<KB2, 512, 0, stream>>>(pts, nor, gind, cinv, vox4,
                                                  Wf2, bf2c, MUb, w2,
                                                  (const int*)nullptr,
                                                  (float*)nullptr, PH2, PQ2);
    }
    k5_bn2<<<1, 256, 0, stream>>>(PH2, PQ2, bn2g, bn2b, s2, t2);
    if (tier == 1) {
        k6_stream<_Float16><<<KB6S, 512, 0, stream>>>(base, (const _Float16*)hbuf, s2, t2, w3, b3, out);
    } else {
        k6_gather<<<KB6, 256, 0, stream>>>(pts, nor, gind, base, pidx, vox4,
                                           Wf2, bf2, w2, b2, s2, t2, out);
        k7_final<<<KB7, 256, 0, stream>>>(vox4, w3, b3, out);
    }
}